// Round 8
// baseline (1309.813 us; speedup 1.0000x reference)
//
#include <hip/hip_runtime.h>
#include <math.h>

#define D 64
#define K 4096
#define MARGIN 0.015f
#define KSPLIT 4
#define CPH (K / 16 / KSPLIT)  // chunks of 16 codes per half = 64

typedef float f32x4 __attribute__((ext_vector_type(4)));
typedef short bf16x8 __attribute__((ext_vector_type(8)));

// RNE fp32 -> bf16 (bit pattern as ushort)
static __device__ inline unsigned short f2bf(float x) {
  unsigned u = __builtin_bit_cast(unsigned, x);
  unsigned r = (u + 0x7FFF + ((u >> 16) & 1)) >> 16;
  return (unsigned short)r;
}
static __device__ inline float bf2f(unsigned short s) {
  unsigned u = ((unsigned)s) << 16;
  return __builtin_bit_cast(float, u);
}

// ---------------------------------------------------------------------------
// e_sq[k] = sum_d emb[k][d]^2  (exact fp32)
// ---------------------------------------------------------------------------
__global__ __launch_bounds__(256) void esq_kernel(const float* __restrict__ emb,
                                                  float* __restrict__ e_sq) {
  int k = blockIdx.x * 256 + threadIdx.x;
  if (k >= K) return;
  const float* e = emb + (size_t)k * D;
  float s = 0.f;
#pragma unroll
  for (int d = 0; d < D; ++d) s = fmaf(e[d], e[d], s);
  e_sq[k] = s;
}

// ---------------------------------------------------------------------------
// Split emb into bf16 hi/lo, PRE-SWIZZLED into MFMA B-fragment order:
// element (code k=c*16+col, dim d=t*32+quad*8+j) -> ((c*2+t)*64 + quad*16+col)*8 + j
// so each B-frag read in dist_kernel is one fully-coalesced 1KB wave load.
// ---------------------------------------------------------------------------
__global__ __launch_bounds__(256) void esplit_kernel(const float* __restrict__ emb,
                                                     short* __restrict__ e_hi,
                                                     short* __restrict__ e_lo) {
  int i = blockIdx.x * 256 + threadIdx.x;  // [0, 256*2*64)
  if (i >= (K / 16) * 2 * 64) return;
  int lane = i & 63;
  int t = (i >> 6) & 1;
  int c = i >> 7;
  int quad = lane >> 4, col = lane & 15;
  const float* src = emb + (size_t)(c * 16 + col) * D + t * 32 + quad * 8;
  f32x4 u0 = *(const f32x4*)src;
  f32x4 u1 = *(const f32x4*)(src + 4);
  bf16x8 h, l;
#pragma unroll
  for (int j = 0; j < 8; ++j) {
    float x = (j < 4) ? u0[j] : u1[j - 4];
    unsigned short hb = f2bf(x);
    h[j] = (short)hb;
    l[j] = (short)f2bf(x - bf2f(hb));
  }
  size_t dst = ((size_t)i) * 8;  // i == (c*2+t)*64 + lane
  *(bf16x8*)(e_hi + dst) = h;
  *(bf16x8*)(e_lo + dst) = l;
}

// ---------------------------------------------------------------------------
// Barrier-free MFMA dist/argmin. Wave owns 64 rows (4 m-tiles) x 1024 codes
// (KSPLIT=4). Round-7 analysis: 32-row waves paid ~4KB of B-frag fetch per
// 512 row-codes and serialized load->wait->compute per chunk. Here B bytes
// per row-code halve AND B is register double-buffered (prefetch chunk c+1
// during chunk c's 24 MFMA + tracking VALU).
// Per-wave VGPR demand ~175 (a 64 + Bx2 32 + track 48 + acc 16 + addr);
// launch_bounds(256,2) caps at 256 -- no forced spill (round-5 trap was
// cap 128 < demand).
// A[m=lane&15][k=quad*8+j]; B[n=lane&15][k=quad*8+j]; C/D row=quad*4+r, col=lane&15.
// ---------------------------------------------------------------------------
__global__ __launch_bounds__(256, 2) void dist_kernel(const float* __restrict__ z_e,
                                                      const short* __restrict__ e_hi,
                                                      const short* __restrict__ e_lo,
                                                      const float* __restrict__ esq,
                                                      float* __restrict__ pbest,
                                                      float* __restrict__ psec,
                                                      int* __restrict__ pidx) {
  const int tid = threadIdx.x;
  const int wv = tid >> 6;
  const int lane = tid & 63;
  const int quad = lane >> 4, col = lane & 15;
  const int rowbase = blockIdx.x * 256 + wv * 64;
  const int half = blockIdx.y;
  const int c0 = half * CPH;

  // ---- A fragments: 4 m-tiles x 2 k-halves, split to bf16 hi/lo ----
  bf16x8 a_hi[4][2], a_lo[4][2];
#pragma unroll
  for (int s = 0; s < 4; ++s) {
#pragma unroll
    for (int t = 0; t < 2; ++t) {
      const float* zr = z_e + (size_t)(rowbase + s * 16 + col) * D + t * 32 + quad * 8;
      f32x4 u0 = *(const f32x4*)zr;
      f32x4 u1 = *(const f32x4*)(zr + 4);
#pragma unroll
      for (int j = 0; j < 8; ++j) {
        float x = (j < 4) ? u0[j] : u1[j - 4];
        unsigned short hb = f2bf(x);
        a_hi[s][t][j] = (short)hb;
        a_lo[s][t][j] = (short)f2bf(x - bf2f(hb));
      }
    }
  }

  float best[16], second[16];
  int bidx[16];
#pragma unroll
  for (int i = 0; i < 16; ++i) {
    best[i] = __builtin_inff();
    second[i] = __builtin_inff();
    bidx[i] = 0;
  }

  const size_t lofs = (size_t)lane * 8;

  // register double-buffer for B frags + esq
  bf16x8 bh[2][2], bl[2][2];
  float esqb[2];
#pragma unroll
  for (int t = 0; t < 2; ++t) {
    bh[0][t] = *(const bf16x8*)(e_hi + (size_t)(c0 * 2 + t) * 512 + lofs);
    bl[0][t] = *(const bf16x8*)(e_lo + (size_t)(c0 * 2 + t) * 512 + lofs);
  }
  esqb[0] = esq[c0 * 16 + col];

  for (int cc = 0; cc < CPH; ++cc) {
    const int cb = cc & 1;
    const int nc = c0 + ((cc + 1 < CPH) ? cc + 1 : cc);  // clamp: harmless re-read
#pragma unroll
    for (int t = 0; t < 2; ++t) {
      bh[cb ^ 1][t] = *(const bf16x8*)(e_hi + (size_t)(nc * 2 + t) * 512 + lofs);
      bl[cb ^ 1][t] = *(const bf16x8*)(e_lo + (size_t)(nc * 2 + t) * 512 + lofs);
    }
    esqb[cb ^ 1] = esq[nc * 16 + col];

    const float esql = esqb[cb];
    const int code = (c0 + cc) * 16 + col;
    const bf16x8 B0h = bh[cb][0], B1h = bh[cb][1];
    const bf16x8 B0l = bl[cb][0], B1l = bl[cb][1];

    f32x4 acc[4];
#pragma unroll
    for (int s = 0; s < 4; ++s) {
      acc[s] = (f32x4){0.f, 0.f, 0.f, 0.f};
      acc[s] = __builtin_amdgcn_mfma_f32_16x16x32_bf16(a_hi[s][0], B0h, acc[s], 0, 0, 0);
      acc[s] = __builtin_amdgcn_mfma_f32_16x16x32_bf16(a_lo[s][0], B0h, acc[s], 0, 0, 0);
      acc[s] = __builtin_amdgcn_mfma_f32_16x16x32_bf16(a_hi[s][0], B0l, acc[s], 0, 0, 0);
      acc[s] = __builtin_amdgcn_mfma_f32_16x16x32_bf16(a_hi[s][1], B1h, acc[s], 0, 0, 0);
      acc[s] = __builtin_amdgcn_mfma_f32_16x16x32_bf16(a_lo[s][1], B1h, acc[s], 0, 0, 0);
      acc[s] = __builtin_amdgcn_mfma_f32_16x16x32_bf16(a_hi[s][1], B1l, acc[s], 0, 0, 0);
    }

#pragma unroll
    for (int s = 0; s < 4; ++s) {
#pragma unroll
      for (int r = 0; r < 4; ++r) {
        float q = fmaf(-2.f, acc[s][r], esql);
        int i = s * 4 + r;
        float ob = best[i];
        best[i] = fminf(ob, q);
        second[i] = __builtin_amdgcn_fmed3f(ob, q, second[i]);
        bidx[i] = (q < ob) ? code : bidx[i];
      }
    }
  }

  // ---- merge across the 16 code-columns (xor over col bits) ----
#pragma unroll
  for (int i = 0; i < 16; ++i) {
    float b = best[i], s2 = second[i];
    int ix = bidx[i];
#pragma unroll
    for (int off = 1; off < 16; off <<= 1) {
      float ob = __shfl_xor(b, off);
      float os = __shfl_xor(s2, off);
      int oi = __shfl_xor(ix, off);
      float ns = fminf(fminf(s2, os), fmaxf(b, ob));
      if (ob < b || (ob == b && oi < ix)) ix = oi;
      b = fminf(b, ob);
      s2 = ns;
    }
    if (col == 0) {
      int row = rowbase + (i >> 2) * 16 + quad * 4 + (i & 3);
      size_t o = (size_t)half * 65536 + row;
      pbest[o] = b;
      psec[o] = s2;
      pidx[o] = ix;
    }
  }
}

// ---------------------------------------------------------------------------
// Merge the KSPLIT partials per row; write best_idx; compact ambiguous rows
// (gap < MARGIN) into a worklist. Halves ascending, strict < -> first-occurrence.
// ---------------------------------------------------------------------------
__global__ __launch_bounds__(256) void merge_kernel(const float* __restrict__ pbest,
                                                    const float* __restrict__ psec,
                                                    const int* __restrict__ pidx,
                                                    int* __restrict__ best_idx,
                                                    int* __restrict__ worklist,
                                                    int* __restrict__ nwork,
                                                    int N) {
  int row = blockIdx.x * 256 + threadIdx.x;
  float b = pbest[row];
  float s2 = psec[row];
  int ix = pidx[row];
#pragma unroll
  for (int h = 1; h < KSPLIT; ++h) {
    size_t o = (size_t)h * 65536 + row;
    float bh = pbest[o];
    float sh = psec[o];
    int ih = pidx[o];
    s2 = fminf(fminf(s2, sh), fmaxf(b, bh));
    if (bh < b) ix = ih;  // strict <: ties keep lower-half (smaller) index
    b = fminf(b, bh);
  }
  best_idx[row] = ix;
  if (s2 - b < MARGIN) {
    int slot = atomicAdd(nwork, 1);
    worklist[slot] = row;
  }
}

// ---------------------------------------------------------------------------
// Candidate-based exact resolve. Per ambiguous row: only a half with
// second_h < B+MARGIN can hide an unknown contender -> exact fp32 scan of
// that 1024-code half. A half with best_h < B+MARGIN <= second_h has exactly
// one candidate (index known) -> one 256B exact dot. ~25% of rows need any
// half-scan => ~15x less L2 traffic than the round-7 full rescan.
// ---------------------------------------------------------------------------
__global__ __launch_bounds__(256, 1) void resolve_kernel(const float* __restrict__ z_e,
                                                         const float* __restrict__ emb,
                                                         const float* __restrict__ esq,
                                                         const float* __restrict__ pbest,
                                                         const float* __restrict__ psec,
                                                         const int* __restrict__ pidx,
                                                         const int* __restrict__ worklist,
                                                         const int* __restrict__ nwork,
                                                         int* __restrict__ best_idx) {
  const int tid = threadIdx.x;
  const int wave = tid >> 6;
  const int lane = tid & 63;
  const int wgid = blockIdx.x * 4 + wave;  // 1024 waves total

  __shared__ float zs[4][D];
  const int n = *nwork;

  for (int j = wgid; j < n; j += 1024) {
    const int row = worklist[j];
    if (lane < 16) ((f32x4*)zs[wave])[lane] = *((const f32x4*)(z_e + (size_t)row * D) + lane);

    float pb[KSPLIT], ps[KSPLIT];
    int pi[KSPLIT];
    float B = __builtin_inff();
#pragma unroll
    for (int h = 0; h < KSPLIT; ++h) {
      size_t o = (size_t)h * 65536 + row;
      pb[h] = pbest[o];
      ps[h] = psec[o];
      pi[h] = pidx[o];
      B = fminf(B, pb[h]);
    }
    const float lim = B + MARGIN;

    float bv = __builtin_inff();
    int bi = 0;
#pragma unroll
    for (int h = 0; h < KSPLIT; ++h) {
      if (ps[h] < lim) {
        // exact fp32 scan of this 1024-code half
        float hb = __builtin_inff();
        int hx = 0;
        for (int t = 0; t < 16; ++t) {
          int c = h * 1024 + t * 64 + lane;
          const f32x4* er = (const f32x4*)(emb + (size_t)c * D);
          f32x4 a = {0.f, 0.f, 0.f, 0.f};
#pragma unroll
          for (int i = 0; i < 16; ++i)
            a = __builtin_elementwise_fma(er[i], ((const f32x4*)zs[wave])[i], a);
          float dot = (a[0] + a[1]) + (a[2] + a[3]);
          float q = fmaf(-2.f, dot, esq[c]);
          if (q < hb) { hb = q; hx = c; }  // ascending t => first occurrence
        }
#pragma unroll
        for (int off = 32; off > 0; off >>= 1) {
          float ov = __shfl_down(hb, off);
          int oi = __shfl_down(hx, off);
          if (ov < hb || (ov == hb && oi < hx)) { hb = ov; hx = oi; }
        }
        hb = __shfl(hb, 0);
        hx = __shfl(hx, 0);
        if (hb < bv || (hb == bv && hx < bi)) { bv = hb; bi = hx; }
      } else if (pb[h] < lim) {
        // single candidate: exact dot for code pi[h]
        int c = pi[h];
        float p = emb[(size_t)c * D + lane] * zs[wave][lane];
#pragma unroll
        for (int off = 1; off < 64; off <<= 1) p += __shfl_xor(p, off);
        float q = fmaf(-2.f, p, esq[c]);
        if (q < bv || (q == bv && c < bi)) { bv = q; bi = c; }
      }
    }
    if (lane == 0) best_idx[row] = bi;
  }
}

// ---------------------------------------------------------------------------
// Gather z_q, write z_q_st + indices, loss partials, histogram.
// ---------------------------------------------------------------------------
__global__ __launch_bounds__(256) void finalize_kernel(const float* __restrict__ z_e,
                                                       const float* __restrict__ emb,
                                                       const int* __restrict__ best_idx,
                                                       float* __restrict__ out_zq,
                                                       float* __restrict__ out_idx,
                                                       int* __restrict__ counts,
                                                       float* __restrict__ block_loss) {
  const int tid = threadIdx.x;
  const int wave = tid >> 6;
  const int lane = tid & 63;
  const int row = blockIdx.x * 4 + wave;

  int bidx = best_idx[row];
  float ze = z_e[(size_t)row * D + lane];
  float zq = emb[(size_t)bidx * D + lane];
  float st = ze + (zq - ze);  // straight-through, same formula as reference
  out_zq[(size_t)row * D + lane] = st;

  float diff = zq - ze;
  float sq = diff * diff;
#pragma unroll
  for (int off = 32; off > 0; off >>= 1) sq += __shfl_down(sq, off);

  __shared__ float ls[4];
  if (lane == 0) {
    ls[wave] = sq;
    out_idx[row] = (float)bidx;
    atomicAdd(&counts[bidx], 1);
  }
  __syncthreads();
  if (tid == 0) block_loss[blockIdx.x] = ls[0] + ls[1] + ls[2] + ls[3];
}

// ---------------------------------------------------------------------------
// Final scalars: commitment loss, perplexity, n_active. Single block.
// ---------------------------------------------------------------------------
__global__ __launch_bounds__(1024) void stats_kernel(const float* __restrict__ block_loss,
                                                     int nblocks,
                                                     const int* __restrict__ counts,
                                                     float* __restrict__ out_scalars,
                                                     int N) {
  const int tid = threadIdx.x;
  const int wave = tid >> 6;
  const int lane = tid & 63;

  float lsum = 0.f;
  for (int i = tid; i < nblocks; i += 1024) lsum += block_loss[i];

  float ent = 0.f;
  int act = 0;
  const float invN = 1.0f / (float)N;
  for (int k = tid; k < K; k += 1024) {
    float p = (float)counts[k] * invN;
    ent += p * logf(p + 1e-10f);
    act += (p > 0.001f) ? 1 : 0;
  }

#pragma unroll
  for (int off = 32; off > 0; off >>= 1) {
    lsum += __shfl_down(lsum, off);
    ent += __shfl_down(ent, off);
    act += __shfl_down(act, off);
  }

  __shared__ float sl[16], se[16];
  __shared__ int sa[16];
  if (lane == 0) { sl[wave] = lsum; se[wave] = ent; sa[wave] = act; }
  __syncthreads();
  if (tid == 0) {
    float L = 0.f, E = 0.f;
    int A = 0;
#pragma unroll
    for (int w = 0; w < 16; ++w) { L += sl[w]; E += se[w]; A += sa[w]; }
    out_scalars[0] = 0.25f * L / ((float)N * (float)D);  // commitment loss
    out_scalars[1] = expf(-E);                            // perplexity
    out_scalars[2] = (float)A;                            // n_active
  }
}

extern "C" void kernel_launch(void* const* d_in, const int* in_sizes, int n_in,
                              void* d_out, int out_size, void* d_ws, size_t ws_size,
                              hipStream_t stream) {
  const float* z_e = (const float*)d_in[0];
  const float* emb = (const float*)d_in[1];
  const int N = in_sizes[0] / D;  // 65536

  float* out = (float*)d_out;
  float* out_zq = out;
  float* out_idx = out + (size_t)N * D;
  float* out_scalars = out + (size_t)N * (D + 1);

  char* ws = (char*)d_ws;
  size_t o = 0;
  int* counts = (int*)(ws + o);      o += 16384;                  // 4096 ints
  int* nwork = (int*)(ws + o);       o += 256;                    // 1 int (+pad)
  float* esq = (float*)(ws + o);     o += 16384;                  // 4096 f32
  short* e_hi = (short*)(ws + o);    o += (size_t)K * D * 2;      // 512 KB
  short* e_lo = (short*)(ws + o);    o += (size_t)K * D * 2;      // 512 KB
  float* pbest = (float*)(ws + o);   o += (size_t)KSPLIT * N * 4; // 1 MB
  float* psec = (float*)(ws + o);    o += (size_t)KSPLIT * N * 4; // 1 MB
  int* pidx = (int*)(ws + o);        o += (size_t)KSPLIT * N * 4; // 1 MB
  int* best_idx = (int*)(ws + o);    o += (size_t)N * 4;          // 256 KB
  int* worklist = (int*)(ws + o);    o += (size_t)N * 4;          // 256 KB
  float* block_loss = (float*)(ws + o);                            // 64 KB

  hipMemsetAsync(counts, 0, 16384 + 256, stream);  // counts + nwork

  esq_kernel<<<K / 256, 256, 0, stream>>>(emb, esq);
  esplit_kernel<<<(K / 16) * 2 * 64 / 256, 256, 0, stream>>>(emb, e_hi, e_lo);
  dist_kernel<<<dim3(N / 256, KSPLIT), 256, 0, stream>>>(z_e, e_hi, e_lo, esq,
                                                         pbest, psec, pidx);
  merge_kernel<<<N / 256, 256, 0, stream>>>(pbest, psec, pidx, best_idx,
                                            worklist, nwork, N);
  resolve_kernel<<<256, 256, 0, stream>>>(z_e, emb, esq, pbest, psec, pidx,
                                          worklist, nwork, best_idx);
  finalize_kernel<<<N / 4, 256, 0, stream>>>(z_e, emb, best_idx, out_zq, out_idx,
                                             counts, block_loss);
  stats_kernel<<<1, 1024, 0, stream>>>(block_loss, N / 4, counts, out_scalars, N);
}

// Round 9
// 248.323 us; speedup vs baseline: 5.2746x; 5.2746x over previous
//
#include <hip/hip_runtime.h>
#include <math.h>

#define D 64
#define K 4096
#define MARGIN 0.015f
#define KSPLIT 4
#define CPH (K / 16 / KSPLIT)  // chunks of 16 codes per half = 64

typedef float f32x4 __attribute__((ext_vector_type(4)));
typedef short bf16x8 __attribute__((ext_vector_type(8)));

// RNE fp32 -> bf16 (bit pattern as ushort)
static __device__ inline unsigned short f2bf(float x) {
  unsigned u = __builtin_bit_cast(unsigned, x);
  unsigned r = (u + 0x7FFF + ((u >> 16) & 1)) >> 16;
  return (unsigned short)r;
}
static __device__ inline float bf2f(unsigned short s) {
  unsigned u = ((unsigned)s) << 16;
  return __builtin_bit_cast(float, u);
}

// ---------------------------------------------------------------------------
// e_sq[k] = sum_d emb[k][d]^2  (exact fp32)
// ---------------------------------------------------------------------------
__global__ __launch_bounds__(256) void esq_kernel(const float* __restrict__ emb,
                                                  float* __restrict__ e_sq) {
  int k = blockIdx.x * 256 + threadIdx.x;
  if (k >= K) return;
  const float* e = emb + (size_t)k * D;
  float s = 0.f;
#pragma unroll
  for (int d = 0; d < D; ++d) s = fmaf(e[d], e[d], s);
  e_sq[k] = s;
}

// ---------------------------------------------------------------------------
// Split emb into bf16 hi/lo, PRE-SWIZZLED into MFMA B-fragment order:
// element (code k=c*16+col, dim d=t*32+quad*8+j) -> ((c*2+t)*64 + quad*16+col)*8 + j
// so each B-frag read in dist_kernel is one fully-coalesced 1KB wave load.
// ---------------------------------------------------------------------------
__global__ __launch_bounds__(256) void esplit_kernel(const float* __restrict__ emb,
                                                     short* __restrict__ e_hi,
                                                     short* __restrict__ e_lo) {
  int i = blockIdx.x * 256 + threadIdx.x;  // [0, 256*2*64)
  if (i >= (K / 16) * 2 * 64) return;
  int lane = i & 63;
  int t = (i >> 6) & 1;
  int c = i >> 7;
  int quad = lane >> 4, col = lane & 15;
  const float* src = emb + (size_t)(c * 16 + col) * D + t * 32 + quad * 8;
  f32x4 u0 = *(const f32x4*)src;
  f32x4 u1 = *(const f32x4*)(src + 4);
  bf16x8 h, l;
#pragma unroll
  for (int j = 0; j < 8; ++j) {
    float x = (j < 4) ? u0[j] : u1[j - 4];
    unsigned short hb = f2bf(x);
    h[j] = (short)hb;
    l[j] = (short)f2bf(x - bf2f(hb));
  }
  size_t dst = ((size_t)i) * 8;  // i == (c*2+t)*64 + lane
  *(bf16x8*)(e_hi + dst) = h;
  *(bf16x8*)(e_lo + dst) = l;
}

// ---------------------------------------------------------------------------
// Barrier-free MFMA dist/argmin — EXACT round-7 structure (known-good:
// VGPR 48, no spills). Wave owns 32 rows (2 m-tiles) x 1024 codes (KSPLIT=4,
// 64 chunks of 16). Round-8 lesson (twice burned): any variant with source
// register demand > ~120 (64-row tile, reg double-buffer) spills tracking
// arrays to AGPRs via v_accvgpr moves -> VALU storm (79% VALU, 3% MFMA).
// Do not grow this wave's state.
// A[m=lane&15][k=quad*8+j]; B[n=lane&15][k=quad*8+j]; C/D row=quad*4+r, col=lane&15.
// ---------------------------------------------------------------------------
__global__ __launch_bounds__(256, 2) void dist_kernel(const float* __restrict__ z_e,
                                                      const short* __restrict__ e_hi,
                                                      const short* __restrict__ e_lo,
                                                      const float* __restrict__ esq,
                                                      float* __restrict__ pbest,
                                                      float* __restrict__ psec,
                                                      int* __restrict__ pidx) {
  const int tid = threadIdx.x;
  const int wv = tid >> 6;
  const int lane = tid & 63;
  const int quad = lane >> 4, col = lane & 15;
  const int rowbase = blockIdx.x * 128 + wv * 32;
  const int half = blockIdx.y;
  const int c0 = half * CPH;

  // ---- A fragments: 2 m-tiles x 2 k-halves, split to bf16 hi/lo ----
  bf16x8 a_hi[2][2], a_lo[2][2];
#pragma unroll
  for (int s = 0; s < 2; ++s) {
#pragma unroll
    for (int t = 0; t < 2; ++t) {
      const float* zr = z_e + (size_t)(rowbase + s * 16 + col) * D + t * 32 + quad * 8;
      f32x4 u0 = *(const f32x4*)zr;
      f32x4 u1 = *(const f32x4*)(zr + 4);
#pragma unroll
      for (int j = 0; j < 8; ++j) {
        float x = (j < 4) ? u0[j] : u1[j - 4];
        unsigned short hb = f2bf(x);
        a_hi[s][t][j] = (short)hb;
        a_lo[s][t][j] = (short)f2bf(x - bf2f(hb));
      }
    }
  }

  float best[8], second[8];
  int bidx[8];
#pragma unroll
  for (int i = 0; i < 8; ++i) {
    best[i] = __builtin_inff();
    second[i] = __builtin_inff();
    bidx[i] = 0;
  }

  const size_t lofs = (size_t)lane * 8;

  for (int cc = 0; cc < CPH; ++cc) {
    const int c = c0 + cc;
    const bf16x8 bh0 = *(const bf16x8*)(e_hi + (size_t)(c * 2 + 0) * 512 + lofs);
    const bf16x8 bh1 = *(const bf16x8*)(e_hi + (size_t)(c * 2 + 1) * 512 + lofs);
    const bf16x8 bl0 = *(const bf16x8*)(e_lo + (size_t)(c * 2 + 0) * 512 + lofs);
    const bf16x8 bl1 = *(const bf16x8*)(e_lo + (size_t)(c * 2 + 1) * 512 + lofs);
    const float esql = esq[c * 16 + col];
    const int code = c * 16 + col;

    f32x4 acc0 = {0.f, 0.f, 0.f, 0.f};
    f32x4 acc1 = {0.f, 0.f, 0.f, 0.f};
    acc0 = __builtin_amdgcn_mfma_f32_16x16x32_bf16(a_hi[0][0], bh0, acc0, 0, 0, 0);
    acc1 = __builtin_amdgcn_mfma_f32_16x16x32_bf16(a_hi[1][0], bh0, acc1, 0, 0, 0);
    acc0 = __builtin_amdgcn_mfma_f32_16x16x32_bf16(a_lo[0][0], bh0, acc0, 0, 0, 0);
    acc1 = __builtin_amdgcn_mfma_f32_16x16x32_bf16(a_lo[1][0], bh0, acc1, 0, 0, 0);
    acc0 = __builtin_amdgcn_mfma_f32_16x16x32_bf16(a_hi[0][0], bl0, acc0, 0, 0, 0);
    acc1 = __builtin_amdgcn_mfma_f32_16x16x32_bf16(a_hi[1][0], bl0, acc1, 0, 0, 0);
    acc0 = __builtin_amdgcn_mfma_f32_16x16x32_bf16(a_hi[0][1], bh1, acc0, 0, 0, 0);
    acc1 = __builtin_amdgcn_mfma_f32_16x16x32_bf16(a_hi[1][1], bh1, acc1, 0, 0, 0);
    acc0 = __builtin_amdgcn_mfma_f32_16x16x32_bf16(a_lo[0][1], bh1, acc0, 0, 0, 0);
    acc1 = __builtin_amdgcn_mfma_f32_16x16x32_bf16(a_lo[1][1], bh1, acc1, 0, 0, 0);
    acc0 = __builtin_amdgcn_mfma_f32_16x16x32_bf16(a_hi[0][1], bl1, acc0, 0, 0, 0);
    acc1 = __builtin_amdgcn_mfma_f32_16x16x32_bf16(a_hi[1][1], bl1, acc1, 0, 0, 0);

#pragma unroll
    for (int r = 0; r < 4; ++r) {
      float q = fmaf(-2.f, acc0[r], esql);
      float ob = best[r];
      best[r] = fminf(ob, q);
      second[r] = __builtin_amdgcn_fmed3f(ob, q, second[r]);
      bidx[r] = (q < ob) ? code : bidx[r];
    }
#pragma unroll
    for (int r = 0; r < 4; ++r) {
      float q = fmaf(-2.f, acc1[r], esql);
      float ob = best[4 + r];
      best[4 + r] = fminf(ob, q);
      second[4 + r] = __builtin_amdgcn_fmed3f(ob, q, second[4 + r]);
      bidx[4 + r] = (q < ob) ? code : bidx[4 + r];
    }
  }

  // ---- merge across the 16 code-columns (xor over col bits) ----
#pragma unroll
  for (int i = 0; i < 8; ++i) {
    float b = best[i], s2 = second[i];
    int ix = bidx[i];
#pragma unroll
    for (int off = 1; off < 16; off <<= 1) {
      float ob = __shfl_xor(b, off);
      float os = __shfl_xor(s2, off);
      int oi = __shfl_xor(ix, off);
      float ns = fminf(fminf(s2, os), fmaxf(b, ob));
      if (ob < b || (ob == b && oi < ix)) ix = oi;
      b = fminf(b, ob);
      s2 = ns;
    }
    if (col == 0) {
      int row = rowbase + (i >> 2) * 16 + quad * 4 + (i & 3);
      size_t o = (size_t)half * 65536 + row;
      pbest[o] = b;
      psec[o] = s2;
      pidx[o] = ix;
    }
  }
}

// ---------------------------------------------------------------------------
// Merge the KSPLIT partials per row; write best_idx; compact ambiguous rows
// (gap < MARGIN) into a worklist. Halves ascending, strict < -> first-occurrence.
// ---------------------------------------------------------------------------
__global__ __launch_bounds__(256) void merge_kernel(const float* __restrict__ pbest,
                                                    const float* __restrict__ psec,
                                                    const int* __restrict__ pidx,
                                                    int* __restrict__ best_idx,
                                                    int* __restrict__ worklist,
                                                    int* __restrict__ nwork,
                                                    int N) {
  int row = blockIdx.x * 256 + threadIdx.x;
  float b = pbest[row];
  float s2 = psec[row];
  int ix = pidx[row];
#pragma unroll
  for (int h = 1; h < KSPLIT; ++h) {
    size_t o = (size_t)h * 65536 + row;
    float bh = pbest[o];
    float sh = psec[o];
    int ih = pidx[o];
    s2 = fminf(fminf(s2, sh), fmaxf(b, bh));
    if (bh < b) ix = ih;  // strict <: ties keep lower-half (smaller) index
    b = fminf(b, bh);
  }
  best_idx[row] = ix;
  if (s2 - b < MARGIN) {
    int slot = atomicAdd(nwork, 1);
    worklist[slot] = row;
  }
}

// ---------------------------------------------------------------------------
// Candidate-based exact resolve (round-8, correctness field-tested). Per
// ambiguous row: a half with second_h < B+MARGIN may hide an unknown
// contender -> exact fp32 scan of that 1024-code half. A half with
// best_h < B+MARGIN <= second_h has exactly one candidate -> one 256B dot.
// ~15x less L2 traffic than a full 4096-code rescan.
// ---------------------------------------------------------------------------
__global__ __launch_bounds__(256, 1) void resolve_kernel(const float* __restrict__ z_e,
                                                         const float* __restrict__ emb,
                                                         const float* __restrict__ esq,
                                                         const float* __restrict__ pbest,
                                                         const float* __restrict__ psec,
                                                         const int* __restrict__ pidx,
                                                         const int* __restrict__ worklist,
                                                         const int* __restrict__ nwork,
                                                         int* __restrict__ best_idx) {
  const int tid = threadIdx.x;
  const int wave = tid >> 6;
  const int lane = tid & 63;
  const int wgid = blockIdx.x * 4 + wave;  // 1024 waves total

  __shared__ float zs[4][D];
  const int n = *nwork;

  for (int j = wgid; j < n; j += 1024) {
    const int row = worklist[j];
    if (lane < 16) ((f32x4*)zs[wave])[lane] = *((const f32x4*)(z_e + (size_t)row * D) + lane);

    float pb[KSPLIT], ps[KSPLIT];
    int pi[KSPLIT];
    float B = __builtin_inff();
#pragma unroll
    for (int h = 0; h < KSPLIT; ++h) {
      size_t o = (size_t)h * 65536 + row;
      pb[h] = pbest[o];
      ps[h] = psec[o];
      pi[h] = pidx[o];
      B = fminf(B, pb[h]);
    }
    const float lim = B + MARGIN;

    float bv = __builtin_inff();
    int bi = 0;
#pragma unroll
    for (int h = 0; h < KSPLIT; ++h) {
      if (ps[h] < lim) {
        // exact fp32 scan of this 1024-code half
        float hb = __builtin_inff();
        int hx = 0;
        for (int t = 0; t < 16; ++t) {
          int c = h * 1024 + t * 64 + lane;
          const f32x4* er = (const f32x4*)(emb + (size_t)c * D);
          f32x4 a = {0.f, 0.f, 0.f, 0.f};
#pragma unroll
          for (int i = 0; i < 16; ++i)
            a = __builtin_elementwise_fma(er[i], ((const f32x4*)zs[wave])[i], a);
          float dot = (a[0] + a[1]) + (a[2] + a[3]);
          float q = fmaf(-2.f, dot, esq[c]);
          if (q < hb) { hb = q; hx = c; }  // ascending t => first occurrence
        }
#pragma unroll
        for (int off = 32; off > 0; off >>= 1) {
          float ov = __shfl_down(hb, off);
          int oi = __shfl_down(hx, off);
          if (ov < hb || (ov == hb && oi < hx)) { hb = ov; hx = oi; }
        }
        hb = __shfl(hb, 0);
        hx = __shfl(hx, 0);
        if (hb < bv || (hb == bv && hx < bi)) { bv = hb; bi = hx; }
      } else if (pb[h] < lim) {
        // single candidate: exact dot for code pi[h]
        int c = pi[h];
        float p = emb[(size_t)c * D + lane] * zs[wave][lane];
#pragma unroll
        for (int off = 1; off < 64; off <<= 1) p += __shfl_xor(p, off);
        float q = fmaf(-2.f, p, esq[c]);
        if (q < bv || (q == bv && c < bi)) { bv = q; bi = c; }
      }
    }
    if (lane == 0) best_idx[row] = bi;
  }
}

// ---------------------------------------------------------------------------
// Gather z_q, write z_q_st + indices, loss partials, histogram.
// ---------------------------------------------------------------------------
__global__ __launch_bounds__(256) void finalize_kernel(const float* __restrict__ z_e,
                                                       const float* __restrict__ emb,
                                                       const int* __restrict__ best_idx,
                                                       float* __restrict__ out_zq,
                                                       float* __restrict__ out_idx,
                                                       int* __restrict__ counts,
                                                       float* __restrict__ block_loss) {
  const int tid = threadIdx.x;
  const int wave = tid >> 6;
  const int lane = tid & 63;
  const int row = blockIdx.x * 4 + wave;

  int bidx = best_idx[row];
  float ze = z_e[(size_t)row * D + lane];
  float zq = emb[(size_t)bidx * D + lane];
  float st = ze + (zq - ze);  // straight-through, same formula as reference
  out_zq[(size_t)row * D + lane] = st;

  float diff = zq - ze;
  float sq = diff * diff;
#pragma unroll
  for (int off = 32; off > 0; off >>= 1) sq += __shfl_down(sq, off);

  __shared__ float ls[4];
  if (lane == 0) {
    ls[wave] = sq;
    out_idx[row] = (float)bidx;
    atomicAdd(&counts[bidx], 1);
  }
  __syncthreads();
  if (tid == 0) block_loss[blockIdx.x] = ls[0] + ls[1] + ls[2] + ls[3];
}

// ---------------------------------------------------------------------------
// Final scalars: commitment loss, perplexity, n_active. Single block.
// ---------------------------------------------------------------------------
__global__ __launch_bounds__(1024) void stats_kernel(const float* __restrict__ block_loss,
                                                     int nblocks,
                                                     const int* __restrict__ counts,
                                                     float* __restrict__ out_scalars,
                                                     int N) {
  const int tid = threadIdx.x;
  const int wave = tid >> 6;
  const int lane = tid & 63;

  float lsum = 0.f;
  for (int i = tid; i < nblocks; i += 1024) lsum += block_loss[i];

  float ent = 0.f;
  int act = 0;
  const float invN = 1.0f / (float)N;
  for (int k = tid; k < K; k += 1024) {
    float p = (float)counts[k] * invN;
    ent += p * logf(p + 1e-10f);
    act += (p > 0.001f) ? 1 : 0;
  }

#pragma unroll
  for (int off = 32; off > 0; off >>= 1) {
    lsum += __shfl_down(lsum, off);
    ent += __shfl_down(ent, off);
    act += __shfl_down(act, off);
  }

  __shared__ float sl[16], se[16];
  __shared__ int sa[16];
  if (lane == 0) { sl[wave] = lsum; se[wave] = ent; sa[wave] = act; }
  __syncthreads();
  if (tid == 0) {
    float L = 0.f, E = 0.f;
    int A = 0;
#pragma unroll
    for (int w = 0; w < 16; ++w) { L += sl[w]; E += se[w]; A += sa[w]; }
    out_scalars[0] = 0.25f * L / ((float)N * (float)D);  // commitment loss
    out_scalars[1] = expf(-E);                            // perplexity
    out_scalars[2] = (float)A;                            // n_active
  }
}

extern "C" void kernel_launch(void* const* d_in, const int* in_sizes, int n_in,
                              void* d_out, int out_size, void* d_ws, size_t ws_size,
                              hipStream_t stream) {
  const float* z_e = (const float*)d_in[0];
  const float* emb = (const float*)d_in[1];
  const int N = in_sizes[0] / D;  // 65536

  float* out = (float*)d_out;
  float* out_zq = out;
  float* out_idx = out + (size_t)N * D;
  float* out_scalars = out + (size_t)N * (D + 1);

  char* ws = (char*)d_ws;
  size_t o = 0;
  int* counts = (int*)(ws + o);      o += 16384;                  // 4096 ints
  int* nwork = (int*)(ws + o);       o += 256;                    // 1 int (+pad)
  float* esq = (float*)(ws + o);     o += 16384;                  // 4096 f32
  short* e_hi = (short*)(ws + o);    o += (size_t)K * D * 2;      // 512 KB
  short* e_lo = (short*)(ws + o);    o += (size_t)K * D * 2;      // 512 KB
  float* pbest = (float*)(ws + o);   o += (size_t)KSPLIT * N * 4; // 1 MB
  float* psec = (float*)(ws + o);    o += (size_t)KSPLIT * N * 4; // 1 MB
  int* pidx = (int*)(ws + o);        o += (size_t)KSPLIT * N * 4; // 1 MB
  int* best_idx = (int*)(ws + o);    o += (size_t)N * 4;          // 256 KB
  int* worklist = (int*)(ws + o);    o += (size_t)N * 4;          // 256 KB
  float* block_loss = (float*)(ws + o);                            // 64 KB

  hipMemsetAsync(counts, 0, 16384 + 256, stream);  // counts + nwork

  esq_kernel<<<K / 256, 256, 0, stream>>>(emb, esq);
  esplit_kernel<<<(K / 16) * 2 * 64 / 256, 256, 0, stream>>>(emb, e_hi, e_lo);
  dist_kernel<<<dim3(N / 128, KSPLIT), 256, 0, stream>>>(z_e, e_hi, e_lo, esq,
                                                         pbest, psec, pidx);
  merge_kernel<<<N / 256, 256, 0, stream>>>(pbest, psec, pidx, best_idx,
                                            worklist, nwork, N);
  resolve_kernel<<<256, 256, 0, stream>>>(z_e, emb, esq, pbest, psec, pidx,
                                          worklist, nwork, best_idx);
  finalize_kernel<<<N / 4, 256, 0, stream>>>(z_e, emb, best_idx, out_zq, out_idx,
                                             counts, block_loss);
  stats_kernel<<<1, 1024, 0, stream>>>(block_loss, N / 4, counts, out_scalars, N);
}